// Round 1
// 102.552 us; speedup vs baseline: 1.1102x; 1.1102x over previous
//
#include <hip/hip_runtime.h>
#include <stdint.h>

#define KCODES 22          // emb rows (codes 0..21)
#define KW     12          // padded uint32 words per cycle row (11 used) -> 48B, 16B-aligned

// Clang vector types (nontemporal builtins reject HIP_vector_type wrappers)
typedef int   int2v   __attribute__((ext_vector_type(2)));
typedef int   int4v   __attribute__((ext_vector_type(4)));
typedef float float4v __attribute__((ext_vector_type(4)));

// ---------------- binned-histogram path ----------------
// Buckets of 128 consecutive cycle ids; edges binned as packed u16:
//   val = (cyc & 127) << 5 | code      (code in [0,22), 5 bits)
// Pass 1: per-block LDS rank counting + 1 cursor atomic per (block,bucket),
//         then plain u16 stores into per-bucket regions. NO scattered RMW atomics.
// Pass 2: one block per bucket: LDS histogram (fast per-CU atomics) fused with
//         the register-resident emb expansion. Global cnt array + memset gone.
#define BSHIFT   7
#define BROWS    128                  // 1 << BSHIFT cycles per bucket
#define BCAP     4096                 // u16 slots per bucket (mean ~767, huge margin)
#define EPT      8                    // edges per thread in pass 1
#define CHUNK    2048                 // 256 * EPT
#define MAXBUCK  1024                 // LDS counter array bound

__global__ __launch_bounds__(256) void bin_edges(
        const int* __restrict__ a2c, const int* __restrict__ x,
        uint32_t* __restrict__ gcur, uint16_t* __restrict__ bins,
        int E, int nbuck) {
    __shared__ uint32_t lcnt[MAXBUCK];
    __shared__ uint32_t lbase[MAXBUCK];
    const int tid = threadIdx.x;
    for (int b = tid; b < nbuck; b += 256) lcnt[b] = 0;
    __syncthreads();

    const int base = blockIdx.x * CHUNK + tid * EPT;
    int atoms[EPT] __attribute__((aligned(16)));
    int cycs[EPT]  __attribute__((aligned(16)));
    if (((E & 3) == 0) && (base + EPT <= E)) {
        // 32B-aligned vector loads (base is a multiple of 8)
        *(int4v*)(atoms + 0) = __builtin_nontemporal_load((const int4v*)(a2c + base));
        *(int4v*)(atoms + 4) = __builtin_nontemporal_load((const int4v*)(a2c + base) + 1);
        *(int4v*)(cycs + 0)  = __builtin_nontemporal_load((const int4v*)(a2c + E + base));
        *(int4v*)(cycs + 4)  = __builtin_nontemporal_load((const int4v*)(a2c + E + base) + 1);
    } else {
#pragma unroll
        for (int j = 0; j < EPT; ++j) {
            int e = base + j;
            atoms[j] = (e < E) ? a2c[e] : 0;
            cycs[j]  = (e < E) ? a2c[E + e] : -1;   // -1 marks invalid
        }
    }

    uint16_t val[EPT], bk[EPT], rk[EPT];
#pragma unroll
    for (int j = 0; j < EPT; ++j) {
        if (cycs[j] >= 0) {
            uint32_t code = (uint32_t)x[atoms[j]];          // 400 KB, L2-resident gather
            uint32_t b    = (uint32_t)cycs[j] >> BSHIFT;
            bk[j]  = (uint16_t)b;
            rk[j]  = (uint16_t)atomicAdd(&lcnt[b], 1u);     // LDS returning atomic: in-block rank
            val[j] = (uint16_t)((((uint32_t)cycs[j] & (BROWS - 1)) << 5) | code);
        } else {
            bk[j] = 0xFFFFu;
        }
    }
    __syncthreads();

    // one cursor atomic per non-empty (block, bucket): ~215k total vs 1.2M before
    for (int b = tid; b < nbuck; b += 256) {
        uint32_t c = lcnt[b];
        lbase[b] = c ? atomicAdd(&gcur[b], c) : 0u;
    }
    __syncthreads();

#pragma unroll
    for (int j = 0; j < EPT; ++j) {
        if (bk[j] != 0xFFFFu) {
            uint32_t idx = lbase[bk[j]] + rk[j];
            if (idx < BCAP)                                  // paranoia guard (never trips: ~100 sigma)
                bins[(size_t)bk[j] * BCAP + idx] = val[j];
        }
    }
}

__global__ __launch_bounds__(256) void hist_expand(
        const uint32_t* __restrict__ gcur, const uint16_t* __restrict__ bins,
        const float* __restrict__ emb, float* __restrict__ out, int num_seg) {
    __shared__ uint32_t hist[BROWS * KW];                    // 6144 B
    const int tid = threadIdx.x;
    const int b   = blockIdx.x;
    const int d4  = tid & 31;    // float4 column index
    const int sub = tid >> 5;    // row-within-iteration 0..7

    // issue emb column loads first so they overlap the LDS histogram phase
    float4v e[KCODES];
#pragma unroll
    for (int k = 0; k < KCODES; ++k)
        e[k] = ((const float4v*)emb)[k * 32 + d4];           // 11 KB table, L1/L2-hot

    for (int i = tid; i < BROWS * KW; i += 256) hist[i] = 0;
    __syncthreads();

    int n = gcur[b]; if (n > BCAP) n = BCAP;
    const uint16_t* bb = bins + (size_t)b * BCAP;
    for (int i = tid; i < n; i += 256) {
        uint32_t v = bb[i];                                  // contiguous, L2-resident
        atomicAdd(&hist[(v >> 5) * KW + ((v & 31u) >> 1)], 1u << ((v & 1u) << 4));
    }
    __syncthreads();

    for (int r = sub; r < BROWS; r += 8) {
        int cyc = b * BROWS + r;
        if (cyc >= num_seg) break;
        const uint4* hrow = (const uint4*)&hist[r * KW];     // same addr across 32 lanes -> broadcast
        uint4 w0 = hrow[0], w1 = hrow[1], w2 = hrow[2];
        uint32_t wv[12] = {w0.x, w0.y, w0.z, w0.w,
                           w1.x, w1.y, w1.z, w1.w,
                           w2.x, w2.y, w2.z, w2.w};
        float4v acc = (float4v)(0.f);
#pragma unroll
        for (int w = 0; w < 11; ++w) {                       // 11 words = codes 0..21
            float c0 = (float)(wv[w] & 0xFFFFu);
            float c1 = (float)(wv[w] >> 16);
            float4v e0 = e[2 * w], e1 = e[2 * w + 1];
            acc.x = fmaf(c1, e1.x, fmaf(c0, e0.x, acc.x));
            acc.y = fmaf(c1, e1.y, fmaf(c0, e0.y, acc.y));
            acc.z = fmaf(c1, e1.z, fmaf(c0, e0.z, acc.z));
            acc.w = fmaf(c1, e1.w, fmaf(c0, e0.w, acc.w));
        }
        // output written once, never re-read -> NT store bypasses L2
        __builtin_nontemporal_store(acc, &((float4v*)out)[(size_t)cyc * 32 + d4]);
    }
}

// ---------------- fallback A: previous atomic-histogram path ----------------
__global__ void count_edges2(const int* __restrict__ a2c,
                             const int* __restrict__ x,
                             uint32_t* __restrict__ cnt, int E) {
    int i = blockIdx.x * blockDim.x + threadIdx.x;
    int E2 = E >> 1;
    if (i < E2) {
        int2v a = __builtin_nontemporal_load(&((const int2v*)a2c)[i]);
        int2v c = __builtin_nontemporal_load(&((const int2v*)(a2c + E))[i]);
        uint32_t k0 = (uint32_t)x[a.x];
        uint32_t k1 = (uint32_t)x[a.y];
        atomicAdd(&cnt[(size_t)c.x * KW + (k0 >> 1)], 1u << ((k0 & 1) << 4));
        atomicAdd(&cnt[(size_t)c.y * KW + (k1 >> 1)], 1u << ((k1 & 1) << 4));
    }
}

__global__ void count_edges1(const int* __restrict__ a2c,
                             const int* __restrict__ x,
                             uint32_t* __restrict__ cnt, int E) {
    int e = blockIdx.x * blockDim.x + threadIdx.x;
    if (e < E) {
        int atom = a2c[e];
        int cyc  = a2c[E + e];
        uint32_t code = (uint32_t)x[atom];
        atomicAdd(&cnt[(size_t)cyc * KW + (code >> 1)], 1u << ((code & 1) << 4));
    }
}

__global__ __launch_bounds__(256) void expand_out(
        const uint32_t* __restrict__ cnt,
        const float* __restrict__ emb,
        float* __restrict__ out, int num_seg) {
    const int d4  = threadIdx.x & 31;
    const int sub = threadIdx.x >> 5;

    float4v e[KCODES];
#pragma unroll
    for (int k = 0; k < KCODES; ++k)
        e[k] = ((const float4v*)emb)[k * 32 + d4];

    for (int c = blockIdx.x * 8 + sub; c < num_seg; c += gridDim.x * 8) {
        const uint4* crow = (const uint4*)(cnt + (size_t)c * KW);
        uint4 w0 = crow[0], w1 = crow[1], w2 = crow[2];
        uint32_t wv[12] = {w0.x, w0.y, w0.z, w0.w,
                           w1.x, w1.y, w1.z, w1.w,
                           w2.x, w2.y, w2.z, w2.w};
        float4v acc = (float4v)(0.f);
#pragma unroll
        for (int w = 0; w < 11; ++w) {
            float c0 = (float)(wv[w] & 0xFFFFu);
            float c1 = (float)(wv[w] >> 16);
            float4v e0 = e[2 * w], e1 = e[2 * w + 1];
            acc.x = fmaf(c1, e1.x, fmaf(c0, e0.x, acc.x));
            acc.y = fmaf(c1, e1.y, fmaf(c0, e0.y, acc.y));
            acc.z = fmaf(c1, e1.z, fmaf(c0, e0.z, acc.z));
            acc.w = fmaf(c1, e1.w, fmaf(c0, e0.w, acc.w));
        }
        __builtin_nontemporal_store(acc, &((float4v*)out)[(size_t)c * 32 + d4]);
    }
}

// ---------------- fallback B (ws tiny): zero + direct atomic scatter ----------------
__global__ void zero_out_f4(float4* __restrict__ out, int n4) {
    int i = blockIdx.x * blockDim.x + threadIdx.x;
    if (i < n4) out[i] = make_float4(0.f, 0.f, 0.f, 0.f);
}

__global__ void scatter_edges(const int* __restrict__ a2c,
                              const int* __restrict__ x,
                              const float* __restrict__ emb,
                              float* __restrict__ out, int E) {
    int t = blockIdx.x * blockDim.x + threadIdx.x;
    int e = t >> 5;
    int d = (t & 31) * 4;
    if (e < E) {
        int atom = a2c[e];
        int cyc  = a2c[E + e];
        int code = x[atom];
        const float4 ev = ((const float4*)emb)[code * 32 + (d >> 2)];
        float* o = out + (size_t)cyc * 128 + d;
        atomicAdd(o + 0, ev.x);
        atomicAdd(o + 1, ev.y);
        atomicAdd(o + 2, ev.z);
        atomicAdd(o + 3, ev.w);
    }
}

extern "C" void kernel_launch(void* const* d_in, const int* in_sizes, int n_in,
                              void* d_out, int out_size, void* d_ws, size_t ws_size,
                              hipStream_t stream) {
    const int*   x    = (const int*)d_in[0];      // [N] codes
    const int*   a2c  = (const int*)d_in[1];      // [2, E]
    const float* emb  = (const float*)d_in[2];    // [22, 128]
    float*       out  = (float*)d_out;

    const int E       = in_sizes[1] / 2;          // 600000
    const int D       = in_sizes[2] / KCODES;     // 128
    const int num_seg = out_size / D;             // 100000

    const int nbuck = (num_seg + BROWS - 1) >> BSHIFT;                    // 782
    const size_t need_bin = 4096 + (size_t)nbuck * BCAP * sizeof(uint16_t); // ~6.4 MB
    const size_t need_cnt = (size_t)num_seg * KW * sizeof(uint32_t);        // ~4.8 MB

    if (nbuck <= MAXBUCK && ws_size >= need_bin) {
        uint32_t* gcur = (uint32_t*)d_ws;
        uint16_t* bins = (uint16_t*)((char*)d_ws + 4096);

        (void)hipMemsetAsync(gcur, 0, (size_t)nbuck * sizeof(uint32_t), stream); // 3 KB, ~free

        int blocks1 = (E + CHUNK - 1) / CHUNK;                 // 293
        bin_edges<<<blocks1, 256, 0, stream>>>(a2c, x, gcur, bins, E, nbuck);
        hist_expand<<<nbuck, 256, 0, stream>>>(gcur, bins, emb, out, num_seg);
    } else if (ws_size >= need_cnt) {
        uint32_t* cnt = (uint32_t*)d_ws;
        (void)hipMemsetAsync(cnt, 0, need_cnt, stream);
        if ((E & 1) == 0) {
            int E2 = E >> 1;
            count_edges2<<<(E2 + 255) / 256, 256, 0, stream>>>(a2c, x, cnt, E);
        } else {
            count_edges1<<<(E + 255) / 256, 256, 0, stream>>>(a2c, x, cnt, E);
        }
        int blocks = (num_seg + 7) / 8;
        if (blocks > 1024) blocks = 1024;
        expand_out<<<blocks, 256, 0, stream>>>(cnt, emb, out, num_seg);
    } else {
        int n4 = out_size / 4;
        zero_out_f4<<<(n4 + 255) / 256, 256, 0, stream>>>((float4*)out, n4);
        long long threads = (long long)E * 32;
        int blocks = (int)((threads + 255) / 256);
        scatter_edges<<<blocks, 256, 0, stream>>>(a2c, x, emb, out, E);
    }
    (void)n_in; (void)D;
}